// Round 3
// baseline (104.136 us; speedup 1.0000x reference)
//
#include <hip/hip_runtime.h>
#include <hip/hip_bf16.h>

// CenterLoss: loss = ( sum_i clamp(||x_i - c_{label_i}||^2, 1e-12, 1e12)
//                      + B*(C-1)*1e-12 ) / B
// R1: 110us -- serialized same-address atomics. R2: partials+reduce, ~22us of
// kernel time inside a ~79us fixed harness-reset envelope (0xAA poison of the
// 256MB ws dominates and flushes L3 every iter).
// R3: 2 rows/wave (32 indep 16B loads in flight/lane), no LDS/barrier in main,
// per-row clamped partials -> d_ws, tiny tree-reduce.

#define BATCH 8192
#define NUM_CLASSES 751
#define FEAT_DIM 2048
#define NB 1024          // blocks; 4 waves/block x 2 rows/wave -> 8192 rows

__global__ __launch_bounds__(256) void center_loss_main(
        const float* __restrict__ x,
        const int* __restrict__ labels,
        const float* __restrict__ centers,
        float* __restrict__ partial) {
    const int t = threadIdx.x;
    const int wave = t >> 6;
    const int lane = t & 63;
    const int r0 = blockIdx.x * 8 + wave * 2;   // rows r0, r0+1

    const int lab0 = labels[r0];
    const int lab1 = labels[r0 + 1];

    const float4* __restrict__ x0 = (const float4*)(x + (size_t)r0 * FEAT_DIM);
    const float4* __restrict__ x1 = (const float4*)(x + (size_t)(r0 + 1) * FEAT_DIM);
    const float4* __restrict__ c0 = (const float4*)(centers + (size_t)lab0 * FEAT_DIM);
    const float4* __restrict__ c1 = (const float4*)(centers + (size_t)lab1 * FEAT_DIM);

    // 512 float4 per row / 64 lanes = 8 float4 per lane per row.
    float acc0 = 0.0f, acc1 = 0.0f;
#pragma unroll
    for (int k = 0; k < 8; ++k) {
        const float4 xa = x0[lane + k * 64];
        const float4 ca = c0[lane + k * 64];
        const float4 xb = x1[lane + k * 64];
        const float4 cb = c1[lane + k * 64];
        float d;
        d = xa.x - ca.x; acc0 += d * d;
        d = xa.y - ca.y; acc0 += d * d;
        d = xa.z - ca.z; acc0 += d * d;
        d = xa.w - ca.w; acc0 += d * d;
        d = xb.x - cb.x; acc1 += d * d;
        d = xb.y - cb.y; acc1 += d * d;
        d = xb.z - cb.z; acc1 += d * d;
        d = xb.w - cb.w; acc1 += d * d;
    }

    // wave(64) shuffle reductions
#pragma unroll
    for (int off = 32; off > 0; off >>= 1) {
        acc0 += __shfl_down(acc0, off, 64);
        acc1 += __shfl_down(acc1, off, 64);
    }

    if (lane == 0) {
        partial[r0]     = fminf(fmaxf(acc0, 1e-12f), 1e12f);
        partial[r0 + 1] = fminf(fmaxf(acc1, 1e-12f), 1e12f);
    }
}

__global__ __launch_bounds__(256) void center_loss_reduce(
        const float* __restrict__ partial,
        float* __restrict__ out) {
    const int t = threadIdx.x;
    float s = 0.0f;
#pragma unroll
    for (int i = 0; i < BATCH / 256; ++i)
        s += partial[t + i * 256];

#pragma unroll
    for (int off = 32; off > 0; off >>= 1)
        s += __shfl_down(s, off, 64);

    __shared__ float ws[4];
    if ((t & 63) == 0) ws[t >> 6] = s;
    __syncthreads();

    if (t == 0) {
        // masked-out zeros -> clamp to 1e-12: (C-1)*1e-12 per row, /B cancels B
        out[0] = (ws[0] + ws[1] + ws[2] + ws[3]) * (1.0f / BATCH) + 7.5e-10f;
    }
}

extern "C" void kernel_launch(void* const* d_in, const int* in_sizes, int n_in,
                              void* d_out, int out_size, void* d_ws, size_t ws_size,
                              hipStream_t stream) {
    const float* x = (const float*)d_in[0];
    const int* labels = (const int*)d_in[1];
    const float* centers = (const float*)d_in[2];
    float* out = (float*)d_out;
    float* partial = (float*)d_ws;   // BATCH floats = 32 KB scratch

    center_loss_main<<<NB, 256, 0, stream>>>(x, labels, centers, partial);
    center_loss_reduce<<<1, 256, 0, stream>>>(partial, out);
}